// Round 11
// baseline (200.506 us; speedup 1.0000x reference)
//
#include <hip/hip_runtime.h>

#define N_TOT  400000
#define NTILE  25000        // N_TOT / 16 voxels per tile
#define NELEM  (N_TOT * 16)
#define CBLK   512          // persistent conv blocks (2 per CU)
#define GS     (CBLK * 4)   // wave grid stride (tiles)

typedef __attribute__((ext_vector_type(8))) short short8;
typedef __attribute__((ext_vector_type(4))) float f32x4;
typedef __attribute__((ext_vector_type(4))) unsigned short us4;
typedef __attribute__((ext_vector_type(4))) int i32x4;

__device__ __forceinline__ unsigned short f2bf(float x) {
    unsigned int u = __float_as_uint(x);
    u += 0x7FFFu + ((u >> 16) & 1u);       // round-to-nearest-even
    return (unsigned short)(u >> 16);
}
__device__ __forceinline__ float bf2f(unsigned short h) {
    return __uint_as_float(((unsigned int)h) << 16);
}

// Build bf16 W-fragments for all 5 layers x 14 k-pairs, and zero the pad voxel
// (index N_TOT) in both bf16 gather buffers. Fragment (lane,slot)->element
// formula is identical for MFMA A- and B-operands on 16x16x32, so this table
// serves as the A-operand (W^T) after the operand swap: lane l slot j holds
// W[2p+(l>>5)][( (l>>4)&1 )*8+j][l&15].
__global__ __launch_bounds__(64) void wfrag_k(const float* __restrict__ w_in,
                                              const float* __restrict__ wbs,
                                              unsigned short* __restrict__ wfrag,
                                              unsigned short* __restrict__ xb,
                                              unsigned short* __restrict__ ob) {
    if (blockIdx.x == 0 && threadIdx.x < 8) {
        us4 z = {0, 0, 0, 0};
        unsigned short* base = (threadIdx.x < 4) ? xb : ob;
        reinterpret_cast<us4*>(base + NELEM)[threadIdx.x & 3] = z;
    }
    int b = blockIdx.x;            // L*14 + p
    int L = b / 14, p = b % 14;
    int l = threadIdx.x;
    int g = l >> 4, col = l & 15;
    int k = 2 * p + (g >> 1);
    int cib = (g & 1) * 8;
    unsigned short v[8];
#pragma unroll
    for (int j = 0; j < 8; ++j) {
        float w = 0.f;
        if (k < 27) {
            int ci = cib + j;
            w = (L == 0) ? w_in[(k * 16 + ci) * 16 + col]
                         : wbs[(((L - 1) * 27 + k) * 16 + ci) * 16 + col];
        }
        v[j] = f2bf(w);
    }
    unsigned short* dst = wfrag + (size_t)(b * 64 + l) * 8;
#pragma unroll
    for (int j = 0; j < 8; ++j) dst[j] = v[j];
}

// Pack neighbor indices once: idxpk[t][j][p] = nbr[2p + (j>>4)][t*16 + (j&15)]
// (center k==13 baked as identity; k>=27 or p>=14 -> -1). Conv lane reads its
// 14 indices with 4 x dwordx4. One 64-lane wave packs two tiles.
__global__ __launch_bounds__(256) void pack_k(const int* __restrict__ nbr,
                                              int* __restrict__ idxpk) {
    int wid  = (blockIdx.x * 256 + threadIdx.x) >> 6;   // 0..12499
    int lane = threadIdx.x & 63;
    int t    = wid * 2 + (lane >> 5);
    int j    = lane & 31;
    int ksel = j >> 4, rc = j & 15;
    int v = t * 16 + rc;
    int I[16];
#pragma unroll
    for (int p = 0; p < 14; ++p) {
        int k = 2 * p + ksel;
        if (k == 13)      I[p] = v;
        else if (k < 27)  I[p] = nbr[(size_t)k * N_TOT + v];
        else              I[p] = -1;
    }
    I[14] = -1; I[15] = -1;
    int* dst = idxpk + ((size_t)t * 32 + j) * 16;
#pragma unroll
    for (int q = 0; q < 4; ++q)
        *reinterpret_cast<i32x4*>(dst + q * 4) =
            *reinterpret_cast<const i32x4*>(&I[q * 4]);
}

__global__ __launch_bounds__(256) void cvt_k(const float* __restrict__ in,
                                             unsigned short* __restrict__ out) {
    int i = (blockIdx.x * 256 + threadIdx.x) * 8;
    f32x4 a = *reinterpret_cast<const f32x4*>(in + i);
    f32x4 b = *reinterpret_cast<const f32x4*>(in + i + 4);
    short8 o = { (short)f2bf(a[0]), (short)f2bf(a[1]), (short)f2bf(a[2]), (short)f2bf(a[3]),
                 (short)f2bf(b[0]), (short)f2bf(b[1]), (short)f2bf(b[2]), (short)f2bf(b[3]) };
    *reinterpret_cast<short8*>(out + i) = o;
}

// Persistent gather-MFMA conv, 3-stage decoupled pipeline per wave. VMEM per
// tile: 4 idx (dwordx4) + 14 gathers + 1 packed 8B store = 19 wave-instrs
// (was 31). Operand swap: W = A-operand, features = B-operand -> C/D rows are
// CHANNELS, so each lane's 4 acc values are 4 contiguous channels of voxel
// rc -> single 8B bf16 store in normal [v][c] layout. Invalid -> zero voxel.
#define IDX(I, tt)                                                              \
  {                                                                             \
    const int* bp = idxpk + ((size_t)(tt) * 32 + jrow) * 16;                    \
    _Pragma("unroll")                                                           \
    for (int q = 0; q < 4; ++q)                                                 \
      *reinterpret_cast<i32x4*>(&I[q * 4]) =                                    \
          *reinterpret_cast<const i32x4*>(bp + q * 4);                          \
  }

#define GAT(A, I)                                                               \
  {                                                                             \
    _Pragma("unroll")                                                           \
    for (int p = 0; p < 14; ++p) {                                              \
      int ci = I[p] < 0 ? N_TOT : I[p];                                         \
      A[p] = *reinterpret_cast<const short8*>(feats + ((size_t)ci << 4) + half);\
    }                                                                           \
  }

#define CMP(A, tt)                                                              \
  {                                                                             \
    f32x4 ac0 = {0.f, 0.f, 0.f, 0.f};                                           \
    f32x4 ac1 = {0.f, 0.f, 0.f, 0.f};                                           \
    _Pragma("unroll")                                                           \
    for (int p = 0; p < 14; p += 2) {                                           \
      ac0 = __builtin_amdgcn_mfma_f32_16x16x32_bf16(W[p],     A[p],     ac0, 0, 0, 0); \
      ac1 = __builtin_amdgcn_mfma_f32_16x16x32_bf16(W[p + 1], A[p + 1], ac1, 0, 0, 0); \
    }                                                                           \
    f32x4 acc = ac0 + ac1;                                                      \
    const int vv = (tt) * 16;                                                   \
    us4 pk = { f2bf(acc[0]), f2bf(acc[1]), f2bf(acc[2]), f2bf(acc[3]) };        \
    *reinterpret_cast<us4*>(raw + ((size_t)(vv + rc) * 16 + hi * 4)) = pk;      \
    _Pragma("unroll")                                                           \
    for (int i = 0; i < 4; ++i) {                                               \
      s_acc[i] += acc[i];                                                       \
      q_acc[i] += acc[i] * acc[i];                                              \
    }                                                                           \
  }

__global__ __launch_bounds__(256, 2) void conv_k(const unsigned short* __restrict__ feats,
                                                 const int* __restrict__ idxpk,
                                                 const unsigned short* __restrict__ wfrag,
                                                 unsigned short* __restrict__ raw,
                                                 float* __restrict__ partials) {
    __shared__ float red[128];

    const int lane = threadIdx.x & 63;
    const int wv   = threadIdx.x >> 6;
    const int hi   = lane >> 4;        // fragment k-block
    const int rc   = lane & 15;        // B-col = voxel in tile; A-row = channel
    const int half = (hi & 1) * 8;     // which 8 input channels this lane loads
    const int ksel = hi >> 1;          // which offset of the pair
    const int jrow = ksel * 16 + rc;   // row in idxpk tile-table

    // loop-invariant W-fragments: 14 x short8 = 56 VGPRs, loaded once per wave
    short8 W[14];
#pragma unroll
    for (int p = 0; p < 14; ++p)
        W[p] = *reinterpret_cast<const short8*>(wfrag + (size_t)(p * 64 + lane) * 8);

    float s_acc[4] = {0.f, 0.f, 0.f, 0.f};
    float q_acc[4] = {0.f, 0.f, 0.f, 0.f};

    int I0[16], I1[16];
    short8 A0[14], A1[14];

    int t0 = blockIdx.x * 4 + wv;
    IDX(I0, t0);
    GAT(A0, I0);                       // one exposed stall at prologue
    int t1 = t0 + GS;
    if (t1 < NTILE) IDX(I1, t1);

    for (;;) {
        // invariant: A0 in flight for t0; I1 in flight/arrived for t1
        int t2 = t0 + 2 * GS;
        if (t2 < NTILE) IDX(I0, t2);
        if (t1 < NTILE) GAT(A1, I1);
        __builtin_amdgcn_sched_barrier(0);
        CMP(A0, t0);
        if (t1 >= NTILE) break;

        int t3 = t1 + 2 * GS;
        if (t3 < NTILE) IDX(I1, t3);
        if (t2 < NTILE) GAT(A0, I0);
        __builtin_amdgcn_sched_barrier(0);
        CMP(A1, t1);
        if (t2 >= NTILE) break;

        t0 = t2;
        t1 = t2 + GS;
    }

    // BN partials: lane (hi,rc) holds channels hi*4+i summed over its voxels;
    // reduce over rc within each 16-lane group, then across waves via LDS.
#pragma unroll
    for (int i = 0; i < 4; ++i) {
        s_acc[i] += __shfl_xor(s_acc[i], 1);  s_acc[i] += __shfl_xor(s_acc[i], 2);
        s_acc[i] += __shfl_xor(s_acc[i], 4);  s_acc[i] += __shfl_xor(s_acc[i], 8);
        q_acc[i] += __shfl_xor(q_acc[i], 1);  q_acc[i] += __shfl_xor(q_acc[i], 2);
        q_acc[i] += __shfl_xor(q_acc[i], 4);  q_acc[i] += __shfl_xor(q_acc[i], 8);
    }
    if (rc == 0) {
#pragma unroll
        for (int i = 0; i < 4; ++i) {
            red[wv * 32 + hi * 4 + i]      = s_acc[i];
            red[wv * 32 + 16 + hi * 4 + i] = q_acc[i];
        }
    }
    __syncthreads();
    if (threadIdx.x < 32) {
        float v = red[threadIdx.x] + red[32 + threadIdx.x] +
                  red[64 + threadIdx.x] + red[96 + threadIdx.x];
        partials[(size_t)threadIdx.x * CBLK + blockIdx.x] = v;
    }
}

__global__ __launch_bounds__(256) void reduce_k(const float* __restrict__ partials,
                                                float* __restrict__ S) {
    int c = blockIdx.x;  // 0..31 (16 sums, 16 sumsqs)
    float s = 0.f;
    for (int i = threadIdx.x; i < CBLK; i += 256) s += partials[(size_t)c * CBLK + i];
    __shared__ float red[256];
    red[threadIdx.x] = s;
    __syncthreads();
#pragma unroll
    for (int off = 128; off > 0; off >>= 1) {
        if (threadIdx.x < off) red[threadIdx.x] += red[threadIdx.x + off];
        __syncthreads();
    }
    if (threadIdx.x == 0) S[c] = red[0];
}

// BN finalize fused; reads raw bf16 conv output, optional bf16 residual,
// writes bf16 feature buffer and/or f32 final output. 8 elems/thread.
__global__ __launch_bounds__(256) void apply_k(const unsigned short* __restrict__ raw,
                                               const float* __restrict__ S,
                                               const float* __restrict__ gamma,
                                               const float* __restrict__ beta,
                                               const unsigned short* residb,
                                               unsigned short* bfout,
                                               float* f32out) {
    int i = (blockIdx.x * 256 + threadIdx.x) * 8;
    int c0 = i & 8;                    // channels c0..c0+7
    short8 r8 = *reinterpret_cast<const short8*>(raw + i);
    float res[8] = {0, 0, 0, 0, 0, 0, 0, 0};
    if (residb) {
        short8 x8 = *reinterpret_cast<const short8*>(residb + i);
#pragma unroll
        for (int j = 0; j < 8; ++j) res[j] = bf2f((unsigned short)x8[j]);
    }
    const float inv = 1.0f / (float)N_TOT;
    float val[8];
#pragma unroll
    for (int j = 0; j < 8; ++j) {
        int c = c0 + j;
        float m   = S[c] * inv;
        float var = S[16 + c] * inv - m * m;
        float sc  = gamma[c] * rsqrtf(var + 1e-3f);
        float sh  = beta[c] - m * sc;
        val[j] = fmaxf(bf2f((unsigned short)r8[j]) * sc + sh + res[j], 0.f);
    }
    if (bfout) {
        short8 o = { (short)f2bf(val[0]), (short)f2bf(val[1]), (short)f2bf(val[2]), (short)f2bf(val[3]),
                     (short)f2bf(val[4]), (short)f2bf(val[5]), (short)f2bf(val[6]), (short)f2bf(val[7]) };
        *reinterpret_cast<short8*>(bfout + i) = o;
    }
    if (f32out) {
        f32x4 lo = { val[0], val[1], val[2], val[3] };
        f32x4 hi = { val[4], val[5], val[6], val[7] };
        *reinterpret_cast<f32x4*>(f32out + i)     = lo;
        *reinterpret_cast<f32x4*>(f32out + i + 4) = hi;
    }
}

extern "C" void kernel_launch(void* const* d_in, const int* in_sizes, int n_in,
                              void* d_out, int out_size, void* d_ws, size_t ws_size,
                              hipStream_t stream) {
    const float* vf   = (const float*)d_in[0];
    const int*   nbr  = (const int*)  d_in[1];
    const float* w_in = (const float*)d_in[2];
    const float* g_in = (const float*)d_in[3];
    const float* b_in = (const float*)d_in[4];
    const float* wbs  = (const float*)d_in[5];
    const float* gs   = (const float*)d_in[6];
    const float* bs   = (const float*)d_in[7];
    float* out = (float*)d_out;

    char* ws = (char*)d_ws;
    size_t off = 0;
    auto alloc = [&](size_t b) { char* p = ws + off; off += (b + 255) & ~(size_t)255; return p; };
    unsigned short* wfrag = (unsigned short*)alloc((size_t)5 * 14 * 64 * 8 * 2);
    unsigned short* xb    = (unsigned short*)alloc((size_t)(NELEM + 16) * 2);  // bf16 x (+zero voxel)
    unsigned short* ob    = (unsigned short*)alloc((size_t)(NELEM + 16) * 2);  // bf16 o (+zero voxel)
    unsigned short* rb    = (unsigned short*)alloc((size_t)NELEM * 2);         // bf16 raw conv out
    int*            idxpk = (int*)alloc((size_t)NTILE * 32 * 16 * 4);          // 51.2 MB
    float*          part  = (float*)alloc((size_t)32 * CBLK * 4);
    float*          S     = (float*)alloc(32 * 4);

    const int FR = 14 * 64 * 8;  // ushorts per layer of wfrag

    wfrag_k<<<70, 64, 0, stream>>>(w_in, wbs, wfrag, xb, ob);
    pack_k<<<3125, 256, 0, stream>>>(nbr, idxpk);
    cvt_k<<<3125, 256, 0, stream>>>(vf, xb);

    // L0: x0 = relu(bn(conv(vf)))                 -> xb
    conv_k<<<CBLK, 256, 0, stream>>>(xb, idxpk, wfrag, rb, part);
    reduce_k<<<32, 256, 0, stream>>>(part, S);
    apply_k<<<3125, 256, 0, stream>>>(rb, S, g_in, b_in, nullptr, xb, nullptr);

    // L1: o = relu(bn(conv(x0)))                  -> ob
    conv_k<<<CBLK, 256, 0, stream>>>(xb, idxpk, wfrag + FR, rb, part);
    reduce_k<<<32, 256, 0, stream>>>(part, S);
    apply_k<<<3125, 256, 0, stream>>>(rb, S, gs + 0, bs + 0, nullptr, ob, nullptr);

    // L2: x1 = relu(bn(conv(o)) + x0)             -> xb (in place resid)
    conv_k<<<CBLK, 256, 0, stream>>>(ob, idxpk, wfrag + 2 * FR, rb, part);
    reduce_k<<<32, 256, 0, stream>>>(part, S);
    apply_k<<<3125, 256, 0, stream>>>(rb, S, gs + 16, bs + 16, xb, xb, nullptr);

    // L3: o = relu(bn(conv(x1)))                  -> ob
    conv_k<<<CBLK, 256, 0, stream>>>(xb, idxpk, wfrag + 3 * FR, rb, part);
    reduce_k<<<32, 256, 0, stream>>>(part, S);
    apply_k<<<3125, 256, 0, stream>>>(rb, S, gs + 32, bs + 32, nullptr, ob, nullptr);

    // L4: out = relu(bn(conv(o)) + x1)            -> d_out (f32)
    conv_k<<<CBLK, 256, 0, stream>>>(ob, idxpk, wfrag + 4 * FR, rb, part);
    reduce_k<<<32, 256, 0, stream>>>(part, S);
    apply_k<<<3125, 256, 0, stream>>>(rb, S, gs + 48, bs + 48, xb, nullptr, out);
}

// Round 12
// 176.543 us; speedup vs baseline: 1.1357x; 1.1357x over previous
//
#include <hip/hip_runtime.h>

#define N_TOT  400000
#define NTILE  25000        // N_TOT / 16 voxels per tile
#define NELEM  (N_TOT * 16)
#define CBLK   1024         // persistent conv blocks (4 per CU)
#define GS     (CBLK * 4)   // wave grid stride (tiles)

typedef __attribute__((ext_vector_type(8))) short short8;
typedef __attribute__((ext_vector_type(4))) float f32x4;
typedef __attribute__((ext_vector_type(4))) unsigned short us4;

__device__ __forceinline__ unsigned short f2bf(float x) {
    unsigned int u = __float_as_uint(x);
    u += 0x7FFFu + ((u >> 16) & 1u);       // round-to-nearest-even
    return (unsigned short)(u >> 16);
}
__device__ __forceinline__ float bf2f(unsigned short h) {
    return __uint_as_float(((unsigned int)h) << 16);
}

// Build bf16 W-fragments for all 5 layers x 14 k-pairs, and zero the pad voxel
// (index N_TOT) in both bf16 gather buffers. Fragment (lane,slot)->element is
// identical for MFMA A- and B-operands on 16x16x32; used as the A-operand
// (operand swap): lane l slot j holds W[2p+(l>>5)][((l>>4)&1)*8+j][l&15].
__global__ __launch_bounds__(64) void wfrag_k(const float* __restrict__ w_in,
                                              const float* __restrict__ wbs,
                                              unsigned short* __restrict__ wfrag,
                                              unsigned short* __restrict__ xb,
                                              unsigned short* __restrict__ ob) {
    if (blockIdx.x == 0 && threadIdx.x < 8) {
        us4 z = {0, 0, 0, 0};
        unsigned short* base = (threadIdx.x < 4) ? xb : ob;
        reinterpret_cast<us4*>(base + NELEM)[threadIdx.x & 3] = z;
    }
    int b = blockIdx.x;            // L*14 + p
    int L = b / 14, p = b % 14;
    int l = threadIdx.x;
    int g = l >> 4, col = l & 15;
    int k = 2 * p + (g >> 1);
    int cib = (g & 1) * 8;
    unsigned short v[8];
#pragma unroll
    for (int j = 0; j < 8; ++j) {
        float w = 0.f;
        if (k < 27) {
            int ci = cib + j;
            w = (L == 0) ? w_in[(k * 16 + ci) * 16 + col]
                         : wbs[(((L - 1) * 27 + k) * 16 + ci) * 16 + col];
        }
        v[j] = f2bf(w);
    }
    unsigned short* dst = wfrag + (size_t)(b * 64 + l) * 8;
#pragma unroll
    for (int j = 0; j < 8; ++j) dst[j] = v[j];
}

__global__ __launch_bounds__(256) void cvt_k(const float* __restrict__ in,
                                             unsigned short* __restrict__ out) {
    int i = (blockIdx.x * 256 + threadIdx.x) * 8;
    f32x4 a = *reinterpret_cast<const f32x4*>(in + i);
    f32x4 b = *reinterpret_cast<const f32x4*>(in + i + 4);
    short8 o = { (short)f2bf(a[0]), (short)f2bf(a[1]), (short)f2bf(a[2]), (short)f2bf(a[3]),
                 (short)f2bf(b[0]), (short)f2bf(b[1]), (short)f2bf(b[2]), (short)f2bf(b[3]) };
    *reinterpret_cast<short8*>(out + i) = o;
}

// Persistent gather-MFMA conv, HALF-TILE (7-pair) pipeline granularity:
//   segment h: idx(h+2) | gathers(h+1) | 7 x MFMA(h)
// Half-size A/I double buffers cut live VGPRs ~165 -> ~115, doubling occupancy
// to 16 waves/CU (the latency-hiding lever). W staged in LDS once per block.
// Operand swap: W = A-operand, features = B-operand -> lane's 4 acc values are
// 4 contiguous channels of voxel rc -> single packed 8B store. Invalid -> zero
// voxel at N_TOT (one coalesced broadcast line).
#define IDXH(I, tt, h)                                                          \
  {                                                                             \
    const int vvh = (tt) * 16;                                                  \
    _Pragma("unroll")                                                           \
    for (int q = 0; q < 7; ++q) {                                               \
      int p = (h) * 7 + q;                                                      \
      int k = 2 * p + ksel;                                                     \
      if (k == 13)      I[q] = vvh + rc;                                        \
      else if (k < 27)  I[q] = nbr[(size_t)k * N_TOT + vvh + rc];               \
      else              I[q] = -1;                                              \
    }                                                                           \
  }

#define GATH(A, I)                                                              \
  {                                                                             \
    _Pragma("unroll")                                                           \
    for (int q = 0; q < 7; ++q) {                                               \
      int ci = I[q] < 0 ? N_TOT : I[q];                                         \
      A[q] = *reinterpret_cast<const short8*>(feats + ((size_t)ci << 4) + half);\
    }                                                                           \
  }

#define CMPH0(A)                                                                \
  {                                                                             \
    _Pragma("unroll")                                                           \
    for (int q = 0; q < 7; ++q) {                                               \
      short8 wf = *reinterpret_cast<const short8*>(&wlds[(q * 64 + lane) * 8]); \
      if (q & 1) ac1 = __builtin_amdgcn_mfma_f32_16x16x32_bf16(wf, A[q], ac1, 0, 0, 0); \
      else       ac0 = __builtin_amdgcn_mfma_f32_16x16x32_bf16(wf, A[q], ac0, 0, 0, 0); \
    }                                                                           \
  }

#define CMPH1(A, tt)                                                            \
  {                                                                             \
    _Pragma("unroll")                                                           \
    for (int q = 0; q < 7; ++q) {                                               \
      int p = q + 7;                                                            \
      short8 wf = *reinterpret_cast<const short8*>(&wlds[(p * 64 + lane) * 8]); \
      if (p & 1) ac1 = __builtin_amdgcn_mfma_f32_16x16x32_bf16(wf, A[q], ac1, 0, 0, 0); \
      else       ac0 = __builtin_amdgcn_mfma_f32_16x16x32_bf16(wf, A[q], ac0, 0, 0, 0); \
    }                                                                           \
    f32x4 acc = ac0 + ac1;                                                      \
    const int vv = (tt) * 16;                                                   \
    us4 pk = { f2bf(acc[0]), f2bf(acc[1]), f2bf(acc[2]), f2bf(acc[3]) };        \
    *reinterpret_cast<us4*>(raw + ((size_t)(vv + rc) * 16 + hi * 4)) = pk;      \
    _Pragma("unroll")                                                           \
    for (int i = 0; i < 4; ++i) {                                               \
      s_acc[i] += acc[i];                                                       \
      q_acc[i] += acc[i] * acc[i];                                              \
    }                                                                           \
    f32x4 zz = {0.f, 0.f, 0.f, 0.f};                                            \
    ac0 = zz; ac1 = zz;                                                         \
  }

__global__ __launch_bounds__(256, 4) void conv_k(const unsigned short* __restrict__ feats,
                                                 const int* __restrict__ nbr,
                                                 const unsigned short* __restrict__ wfrag,
                                                 unsigned short* __restrict__ raw,
                                                 float* __restrict__ partials) {
    __shared__ unsigned short wlds[14 * 64 * 8];   // 14336 B
    __shared__ float red[128];

    {   // cooperative W stage: 14336 B = 896 x 16 B (once per block)
        const f32x4* src = reinterpret_cast<const f32x4*>(wfrag);
        f32x4* dst = reinterpret_cast<f32x4*>(wlds);
        for (int j = threadIdx.x; j < 896; j += 256) dst[j] = src[j];
    }
    __syncthreads();

    const int lane = threadIdx.x & 63;
    const int wv   = threadIdx.x >> 6;
    const int hi   = lane >> 4;        // fragment k-block
    const int rc   = lane & 15;        // B-col = voxel in tile; A-row = channel
    const int half = (hi & 1) * 8;     // which 8 input channels this lane loads
    const int ksel = hi >> 1;          // which offset of the pair

    float s_acc[4] = {0.f, 0.f, 0.f, 0.f};
    float q_acc[4] = {0.f, 0.f, 0.f, 0.f};
    f32x4 ac0 = {0.f, 0.f, 0.f, 0.f};
    f32x4 ac1 = {0.f, 0.f, 0.f, 0.f};

    int Ia[7], Ib[7];
    short8 Aa[7], Ab[7];

    int t = blockIdx.x * 4 + wv;
    IDXH(Ia, t, 0);
    IDXH(Ib, t, 1);
    GATH(Aa, Ia);                      // half0 of t in flight

    for (;;) {
        int tn = t + GS;
        if (tn < NTILE) IDXH(Ia, tn, 0);   // idx 2 halves ahead
        GATH(Ab, Ib);                       // gathers half1 of t
        __builtin_amdgcn_sched_barrier(0);
        CMPH0(Aa);                          // MFMA pairs 0-6 of t

        if (tn < NTILE) {
            IDXH(Ib, tn, 1);                // idx 2 halves ahead
            GATH(Aa, Ia);                   // gathers half0 of tn
        }
        __builtin_amdgcn_sched_barrier(0);
        CMPH1(Ab, t);                       // MFMA pairs 7-13 of t + finish tile

        if (tn >= NTILE) break;
        t = tn;
    }

    // BN partials: lane (hi,rc) holds channels hi*4+i summed over its voxels;
    // reduce over rc within each 16-lane group, then across waves via LDS.
#pragma unroll
    for (int i = 0; i < 4; ++i) {
        s_acc[i] += __shfl_xor(s_acc[i], 1);  s_acc[i] += __shfl_xor(s_acc[i], 2);
        s_acc[i] += __shfl_xor(s_acc[i], 4);  s_acc[i] += __shfl_xor(s_acc[i], 8);
        q_acc[i] += __shfl_xor(q_acc[i], 1);  q_acc[i] += __shfl_xor(q_acc[i], 2);
        q_acc[i] += __shfl_xor(q_acc[i], 4);  q_acc[i] += __shfl_xor(q_acc[i], 8);
    }
    if (rc == 0) {
#pragma unroll
        for (int i = 0; i < 4; ++i) {
            red[wv * 32 + hi * 4 + i]      = s_acc[i];
            red[wv * 32 + 16 + hi * 4 + i] = q_acc[i];
        }
    }
    __syncthreads();
    if (threadIdx.x < 32) {
        float v = red[threadIdx.x] + red[32 + threadIdx.x] +
                  red[64 + threadIdx.x] + red[96 + threadIdx.x];
        partials[(size_t)threadIdx.x * CBLK + blockIdx.x] = v;
    }
}

__global__ __launch_bounds__(256) void reduce_k(const float* __restrict__ partials,
                                                float* __restrict__ S) {
    int c = blockIdx.x;  // 0..31 (16 sums, 16 sumsqs)
    float s = 0.f;
    for (int i = threadIdx.x; i < CBLK; i += 256) s += partials[(size_t)c * CBLK + i];
    __shared__ float red[256];
    red[threadIdx.x] = s;
    __syncthreads();
#pragma unroll
    for (int off = 128; off > 0; off >>= 1) {
        if (threadIdx.x < off) red[threadIdx.x] += red[threadIdx.x + off];
        __syncthreads();
    }
    if (threadIdx.x == 0) S[c] = red[0];
}

// BN finalize fused; reads raw bf16 conv output, optional bf16 residual,
// writes bf16 feature buffer and/or f32 final output. 8 elems/thread.
__global__ __launch_bounds__(256) void apply_k(const unsigned short* __restrict__ raw,
                                               const float* __restrict__ S,
                                               const float* __restrict__ gamma,
                                               const float* __restrict__ beta,
                                               const unsigned short* residb,
                                               unsigned short* bfout,
                                               float* f32out) {
    int i = (blockIdx.x * 256 + threadIdx.x) * 8;
    int c0 = i & 8;                    // channels c0..c0+7
    short8 r8 = *reinterpret_cast<const short8*>(raw + i);
    float res[8] = {0, 0, 0, 0, 0, 0, 0, 0};
    if (residb) {
        short8 x8 = *reinterpret_cast<const short8*>(residb + i);
#pragma unroll
        for (int j = 0; j < 8; ++j) res[j] = bf2f((unsigned short)x8[j]);
    }
    const float inv = 1.0f / (float)N_TOT;
    float val[8];
#pragma unroll
    for (int j = 0; j < 8; ++j) {
        int c = c0 + j;
        float m   = S[c] * inv;
        float var = S[16 + c] * inv - m * m;
        float sc  = gamma[c] * rsqrtf(var + 1e-3f);
        float sh  = beta[c] - m * sc;
        val[j] = fmaxf(bf2f((unsigned short)r8[j]) * sc + sh + res[j], 0.f);
    }
    if (bfout) {
        short8 o = { (short)f2bf(val[0]), (short)f2bf(val[1]), (short)f2bf(val[2]), (short)f2bf(val[3]),
                     (short)f2bf(val[4]), (short)f2bf(val[5]), (short)f2bf(val[6]), (short)f2bf(val[7]) };
        *reinterpret_cast<short8*>(bfout + i) = o;
    }
    if (f32out) {
        f32x4 lo = { val[0], val[1], val[2], val[3] };
        f32x4 hi = { val[4], val[5], val[6], val[7] };
        *reinterpret_cast<f32x4*>(f32out + i)     = lo;
        *reinterpret_cast<f32x4*>(f32out + i + 4) = hi;
    }
}

extern "C" void kernel_launch(void* const* d_in, const int* in_sizes, int n_in,
                              void* d_out, int out_size, void* d_ws, size_t ws_size,
                              hipStream_t stream) {
    const float* vf   = (const float*)d_in[0];
    const int*   nbr  = (const int*)  d_in[1];
    const float* w_in = (const float*)d_in[2];
    const float* g_in = (const float*)d_in[3];
    const float* b_in = (const float*)d_in[4];
    const float* wbs  = (const float*)d_in[5];
    const float* gs   = (const float*)d_in[6];
    const float* bs   = (const float*)d_in[7];
    float* out = (float*)d_out;

    char* ws = (char*)d_ws;
    size_t off = 0;
    auto alloc = [&](size_t b) { char* p = ws + off; off += (b + 255) & ~(size_t)255; return p; };
    unsigned short* wfrag = (unsigned short*)alloc((size_t)5 * 14 * 64 * 8 * 2);
    unsigned short* xb    = (unsigned short*)alloc((size_t)(NELEM + 16) * 2);  // bf16 x (+zero voxel)
    unsigned short* ob    = (unsigned short*)alloc((size_t)(NELEM + 16) * 2);  // bf16 o (+zero voxel)
    unsigned short* rb    = (unsigned short*)alloc((size_t)NELEM * 2);         // bf16 raw conv out
    float*          part  = (float*)alloc((size_t)32 * CBLK * 4);
    float*          S     = (float*)alloc(32 * 4);

    const int FR = 14 * 64 * 8;  // ushorts per layer of wfrag

    wfrag_k<<<70, 64, 0, stream>>>(w_in, wbs, wfrag, xb, ob);
    cvt_k<<<3125, 256, 0, stream>>>(vf, xb);

    // L0: x0 = relu(bn(conv(vf)))                 -> xb
    conv_k<<<CBLK, 256, 0, stream>>>(xb, nbr, wfrag, rb, part);
    reduce_k<<<32, 256, 0, stream>>>(part, S);
    apply_k<<<3125, 256, 0, stream>>>(rb, S, g_in, b_in, nullptr, xb, nullptr);

    // L1: o = relu(bn(conv(x0)))                  -> ob
    conv_k<<<CBLK, 256, 0, stream>>>(xb, nbr, wfrag + FR, rb, part);
    reduce_k<<<32, 256, 0, stream>>>(part, S);
    apply_k<<<3125, 256, 0, stream>>>(rb, S, gs + 0, bs + 0, nullptr, ob, nullptr);

    // L2: x1 = relu(bn(conv(o)) + x0)             -> xb (in place resid)
    conv_k<<<CBLK, 256, 0, stream>>>(ob, nbr, wfrag + 2 * FR, rb, part);
    reduce_k<<<32, 256, 0, stream>>>(part, S);
    apply_k<<<3125, 256, 0, stream>>>(rb, S, gs + 16, bs + 16, xb, xb, nullptr);

    // L3: o = relu(bn(conv(x1)))                  -> ob
    conv_k<<<CBLK, 256, 0, stream>>>(xb, nbr, wfrag + 3 * FR, rb, part);
    reduce_k<<<32, 256, 0, stream>>>(part, S);
    apply_k<<<3125, 256, 0, stream>>>(rb, S, gs + 32, bs + 32, nullptr, ob, nullptr);

    // L4: out = relu(bn(conv(o)) + x1)            -> d_out (f32)
    conv_k<<<CBLK, 256, 0, stream>>>(ob, nbr, wfrag + 4 * FR, rb, part);
    reduce_k<<<32, 256, 0, stream>>>(part, S);
    apply_k<<<3125, 256, 0, stream>>>(rb, S, gs + 48, bs + 48, xb, nullptr, out);
}